// Round 1
// baseline (29245.166 us; speedup 1.0000x reference)
//
#include <hip/hip_runtime.h>

#define NB 512
#define NT 274
#define ND 256
#define NH 512
#define NHH 1024
#define NPOS (NB*NT)
#define EPSF 1e-5f

typedef float f32x4 __attribute__((ext_vector_type(4)));
typedef unsigned int u32x4 __attribute__((ext_vector_type(4)));

__device__ __forceinline__ float bf2f(unsigned short s) {
    unsigned int u = ((unsigned int)s) << 16;
    float f; __builtin_memcpy(&f, &u, 4); return f;
}
__device__ __forceinline__ unsigned short f2bf(float f) {
    unsigned int u; __builtin_memcpy(&u, &f, 4);
    unsigned int r = u + 0x7FFFu + ((u >> 16) & 1u);   // round-to-nearest-even
    return (unsigned short)(r >> 16);
}

// ---------------- init: h = x[:,:,None]*w_in + b_in + pos ----------------
__global__ __launch_bounds__(256) void k_init(const float* __restrict__ x,
    const float* __restrict__ w_in, const float* __restrict__ b_in,
    const float* __restrict__ pos, float* __restrict__ h)
{
    int row = blockIdx.x;              // 0..NPOS-1  (b*NT + t)
    int d = threadIdx.x;
    int t = row % NT;
    float xv = x[row];
    h[(size_t)row*ND + d] = fmaf(xv, w_in[d], b_in[d] + pos[t*ND + d]);
}

// ---------------- prep: outw (f32) -> bf16 copy ----------------
__global__ __launch_bounds__(256) void k_prep(const float* __restrict__ outw,
    unsigned short* __restrict__ ob)
{
    int i = blockIdx.x*256 + threadIdx.x;   // exactly L*D*H = 524288
    ob[i] = f2bf(outw[i]);
}

// ---------------- kA: LN + grouped in-proj + silu/sigmoid ----------------
__global__ __launch_bounds__(256) void kA(const float* __restrict__ h,
    const float* __restrict__ lng, const float* __restrict__ lnb,
    const float* __restrict__ inw, const float* __restrict__ inb,
    unsigned short* __restrict__ u_ws, unsigned short* __restrict__ g_ws)
{
    const int b  = blockIdx.y;
    const int t0 = blockIdx.x * 8;
    const int P  = min(8, NT - t0);
    const int tid = threadIdx.x;
    const int lane = tid & 63, wvi = tid >> 6;
    __shared__ float yl[8][ND];
    __shared__ float2 part[8][4];
    float hv[8];
    #pragma unroll
    for (int p = 0; p < 8; ++p) {
        if (p < P) {
            float v = h[((size_t)b*NT + t0 + p)*ND + tid];
            hv[p] = v;
            float s = v, s2 = v*v;
            #pragma unroll
            for (int off = 32; off; off >>= 1) {
                s  += __shfl_down(s, off);
                s2 += __shfl_down(s2, off);
            }
            if (lane == 0) part[p][wvi] = make_float2(s, s2);
        }
    }
    __syncthreads();
    const float gsc = lng[tid], gbi = lnb[tid];
    #pragma unroll
    for (int p = 0; p < 8; ++p) {
        if (p < P) {
            float2 a0 = part[p][0], a1 = part[p][1], a2 = part[p][2], a3 = part[p][3];
            float S  = a0.x + a1.x + a2.x + a3.x;
            float S2 = a0.y + a1.y + a2.y + a3.y;
            float mu  = S * (1.0f/ND);
            float var = S2 * (1.0f/ND) - mu*mu;
            float rs  = rsqrtf(var + EPSF);
            yl[p][tid] = (hv[p] - mu) * rs * gsc + gbi;
        } else {
            yl[p][tid] = 0.0f;
        }
    }
    __syncthreads();
    // grouped in-proj: 1024 outputs, each uses 32 inputs of its group
    for (int cc = 0; cc < 4; ++cc) {
        const int c = tid + 256*cc;          // 0..1023 ; c = g*128 + o
        const int g = c >> 7;
        const float4* wr = reinterpret_cast<const float4*>(inw + c*32);
        float w[32];
        #pragma unroll
        for (int i = 0; i < 8; ++i) {
            float4 f = wr[i];
            w[4*i+0]=f.x; w[4*i+1]=f.y; w[4*i+2]=f.z; w[4*i+3]=f.w;
        }
        float acc[8];
        #pragma unroll
        for (int p = 0; p < 8; ++p) acc[p] = 0.0f;
        #pragma unroll
        for (int i = 0; i < 32; ++i) {
            float wv = w[i];
            #pragma unroll
            for (int p = 0; p < 8; ++p) acc[p] = fmaf(wv, yl[p][g*32 + i], acc[p]);
        }
        const float bia = inb[c];
        #pragma unroll
        for (int p = 0; p < 8; ++p) {
            if (p < P) {
                float tv = acc[p] + bia;
                float sg = 1.0f / (1.0f + __expf(-tv));
                size_t base = ((size_t)b*NT + t0 + p)*NH;
                if (c < NH) u_ws[base + c]      = f2bf(tv * sg);   // silu
                else        g_ws[base + c - NH] = f2bf(sg);        // sigmoid(gate)
            }
        }
    }
}

// ------- kB: symmetric depthwise conv (K=7) + grouped mix + gate-mult -------
__global__ __launch_bounds__(256) void kB(const unsigned short* __restrict__ u_ws,
    const unsigned short* __restrict__ g_ws, const float* __restrict__ dww,
    const float* __restrict__ mixw, const float* __restrict__ mixb,
    unsigned short* __restrict__ v_ws)
{
    const int b  = blockIdx.y;
    const int t0 = blockIdx.x * 16;
    const int P  = min(16, NT - t0);
    const int tid = threadIdx.x;
    __shared__ unsigned short ul[22][NH];   // halo tile: rows t0-3 .. t0+18
    __shared__ float ucl[16][NH];
    for (int idx = tid; idx < 22*256; idx += 256) {
        int r  = idx >> 8;
        int c2 = idx & 255;
        int t  = t0 - 3 + r;
        unsigned int val = 0u;
        if (t >= 0 && t < NT)
            val = reinterpret_cast<const unsigned int*>(u_ws + ((size_t)b*NT + t)*NH)[c2];
        reinterpret_cast<unsigned int*>(&ul[r][0])[c2] = val;
    }
    __syncthreads();
    // conv: thread owns channels 2*tid, 2*tid+1
    {
        const int c0 = 2*tid;
        float wa[7], wb[7];
        #pragma unroll
        for (int k = 0; k < 7; ++k) { wa[k] = dww[c0*7 + k]; wb[k] = dww[(c0+1)*7 + k]; }
        float wsa[7], wsb[7];
        #pragma unroll
        for (int k = 0; k < 7; ++k) { wsa[k] = 0.5f*(wa[k]+wa[6-k]); wsb[k] = 0.5f*(wb[k]+wb[6-k]); }
        #pragma unroll
        for (int p = 0; p < 16; ++p) {
            float s0 = 0.0f, s1 = 0.0f;
            #pragma unroll
            for (int k = 0; k < 7; ++k) {
                unsigned int raw = *reinterpret_cast<const unsigned int*>(&ul[p+k][c0]);
                s0 = fmaf(bf2f((unsigned short)(raw & 0xffffu)), wsa[k], s0);
                s1 = fmaf(bf2f((unsigned short)(raw >> 16)),     wsb[k], s1);
            }
            *reinterpret_cast<float2*>(&ucl[p][c0]) = make_float2(s0, s1);
        }
    }
    __syncthreads();
    // grouped mix (G=8, 64->64 per group) + gate multiply
    for (int half = 0; half < 2; ++half) {
        const int c = tid + 256*half;        // 0..511 ; group = c>>6
        const int g = c >> 6;
        const float4* wr = reinterpret_cast<const float4*>(mixw + c*64);
        float w[64];
        #pragma unroll
        for (int i = 0; i < 16; ++i) {
            float4 f = wr[i];
            w[4*i+0]=f.x; w[4*i+1]=f.y; w[4*i+2]=f.z; w[4*i+3]=f.w;
        }
        float acc[16];
        #pragma unroll
        for (int p = 0; p < 16; ++p) acc[p] = 0.0f;
        #pragma unroll
        for (int i = 0; i < 64; ++i) {
            float wv = w[i];
            #pragma unroll
            for (int p = 0; p < 16; ++p) acc[p] = fmaf(wv, ucl[p][g*64 + i], acc[p]);
        }
        const float bia = mixb[c];
        #pragma unroll
        for (int p = 0; p < 16; ++p) {
            if (p < P) {
                size_t base = ((size_t)b*NT + t0 + p)*NH;
                float gate = bf2f(g_ws[base + c]);
                v_ws[base + c] = f2bf((acc[p] + bia) * gate);
            }
        }
    }
}

// ------- kC: out-proj GEMM (bf16 MFMA 16x16x32) + bias + residual -------
__global__ __launch_bounds__(256) void kC(const unsigned short* __restrict__ v_ws,
    const unsigned short* __restrict__ outw_b, const float* __restrict__ outb,
    float* __restrict__ h)
{
    const int d0 = blockIdx.x * 64;            // 4 d-tiles (fastest -> L2 reuse of v rows)
    const int m0 = blockIdx.y * 64;            // 2192 m-tiles
    const int lane = threadIdx.x & 63;
    const int wvi  = threadIdx.x >> 6;
    const int arow = m0 + wvi*16 + (lane & 15);
    const int kof  = (lane >> 4) * 8;
    f32x4 acc[4];
    #pragma unroll
    for (int nt = 0; nt < 4; ++nt) acc[nt] = (f32x4){0.f,0.f,0.f,0.f};
    const unsigned short* abase = v_ws  + (size_t)arow*NH + kof;
    const unsigned short* bbase = outw_b + (size_t)(d0 + (lane & 15))*NH + kof;
    #pragma unroll
    for (int ks = 0; ks < 16; ++ks) {
        u32x4 af = *reinterpret_cast<const u32x4*>(abase + ks*32);
        #pragma unroll
        for (int nt = 0; nt < 4; ++nt) {
            u32x4 bfv = *reinterpret_cast<const u32x4*>(bbase + (size_t)nt*16*NH + ks*32);
            asm("v_mfma_f32_16x16x32_bf16 %0, %1, %2, %0"
                : "+v"(acc[nt]) : "v"(af), "v"(bfv));
        }
    }
    const int crow = m0 + wvi*16 + (lane >> 4)*4;
    #pragma unroll
    for (int nt = 0; nt < 4; ++nt) {
        int d = d0 + nt*16 + (lane & 15);
        float ob = outb[d];
        #pragma unroll
        for (int r = 0; r < 4; ++r) {
            size_t off = (size_t)(crow + r)*ND + d;
            h[off] += acc[nt][r] + ob;
        }
    }
}

// ---------------- final layernorm (in place) ----------------
__global__ __launch_bounds__(256) void kLN(float* __restrict__ h,
    const float* __restrict__ g, const float* __restrict__ bb)
{
    const int row = blockIdx.x;
    const int tid = threadIdx.x;
    const int lane = tid & 63, wvi = tid >> 6;
    __shared__ float2 part[4];
    float v = h[(size_t)row*ND + tid];
    float s = v, s2 = v*v;
    #pragma unroll
    for (int off = 32; off; off >>= 1) { s += __shfl_down(s, off); s2 += __shfl_down(s2, off); }
    if (lane == 0) part[wvi] = make_float2(s, s2);
    __syncthreads();
    float2 a0 = part[0], a1 = part[1], a2 = part[2], a3 = part[3];
    float S  = a0.x+a1.x+a2.x+a3.x;
    float S2 = a0.y+a1.y+a2.y+a3.y;
    float mu  = S*(1.0f/ND);
    float var = S2*(1.0f/ND) - mu*mu;
    float rs  = rsqrtf(var + EPSF);
    h[(size_t)row*ND + tid] = (v - mu)*rs*g[tid] + bb[tid];
}

extern "C" void kernel_launch(void* const* d_in, const int* in_sizes, int n_in,
                              void* d_out, int out_size, void* d_ws, size_t ws_size,
                              hipStream_t stream)
{
    const float* x    = (const float*)d_in[0];
    const float* w_in = (const float*)d_in[1];
    const float* b_in = (const float*)d_in[2];
    const float* pos  = (const float*)d_in[3];
    const float* ln_g = (const float*)d_in[4];
    const float* ln_b = (const float*)d_in[5];
    const float* inw  = (const float*)d_in[6];
    const float* inb  = (const float*)d_in[7];
    const float* dww  = (const float*)d_in[8];
    const float* mixw = (const float*)d_in[9];
    const float* mixb = (const float*)d_in[10];
    const float* outw = (const float*)d_in[11];
    const float* outb = (const float*)d_in[12];
    const float* olng = (const float*)d_in[13];
    const float* olnb = (const float*)d_in[14];
    float* h = (float*)d_out;

    const size_t UB = (size_t)NPOS * NH;          // 71,827,456 elems
    unsigned short* u_ws   = (unsigned short*)d_ws;
    unsigned short* g_ws   = u_ws + UB;
    unsigned short* v_ws   = g_ws + UB;
    unsigned short* outw_b = v_ws + UB;           // 4*256*512 bf16

    k_init<<<NPOS, 256, 0, stream>>>(x, w_in, b_in, pos, h);
    k_prep<<<2048, 256, 0, stream>>>(outw, outw_b);
    for (int l = 0; l < 4; ++l) {
        kA<<<dim3(35, NB), 256, 0, stream>>>(h, ln_g + l*ND, ln_b + l*ND,
            inw + (size_t)l*NHH*32, inb + l*NHH, u_ws, g_ws);
        kB<<<dim3(18, NB), 256, 0, stream>>>(u_ws, g_ws, dww + l*NH*7,
            mixw + (size_t)l*NH*64, mixb + l*NH, v_ws);
        kC<<<dim3(4, NPOS/64), 256, 0, stream>>>(v_ws, outw_b + (size_t)l*ND*NH,
            outb + l*ND, h);
    }
    kLN<<<NPOS, 256, 0, stream>>>(h, olng, olnb);
}

// Round 3
// 7092.431 us; speedup vs baseline: 4.1234x; 4.1234x over previous
//
#include <hip/hip_runtime.h>

#define NB 512
#define NT 274
#define ND 256
#define NH 512
#define NHH 1024
#define NPOS (NB*NT)
#define EPSF 1e-5f

typedef float f32x4 __attribute__((ext_vector_type(4)));
typedef unsigned int u32x4 __attribute__((ext_vector_type(4)));

__device__ __forceinline__ float bf2f(unsigned short s) {
    unsigned int u = ((unsigned int)s) << 16;
    float f; __builtin_memcpy(&f, &u, 4); return f;
}
__device__ __forceinline__ unsigned short f2bf(float f) {
    unsigned int u; __builtin_memcpy(&u, &f, 4);
    unsigned int r = u + 0x7FFFu + ((u >> 16) & 1u);   // round-to-nearest-even
    return (unsigned short)(r >> 16);
}

// ---------------- init: h = x[:,:,None]*w_in + b_in + pos ----------------
__global__ __launch_bounds__(256) void k_init(const float* __restrict__ x,
    const float* __restrict__ w_in, const float* __restrict__ b_in,
    const float* __restrict__ pos, float* __restrict__ h)
{
    int row = blockIdx.x;              // 0..NPOS-1  (b*NT + t)
    int d = threadIdx.x;
    int t = row % NT;
    float xv = x[row];
    h[(size_t)row*ND + d] = fmaf(xv, w_in[d], b_in[d] + pos[t*ND + d]);
}

// ------- prep: outw (f32) -> bf16 ; mixw (f32) -> bf16 -------
__global__ __launch_bounds__(256) void k_prep(const float* __restrict__ outw,
    const float* __restrict__ mixw,
    unsigned short* __restrict__ ob, unsigned short* __restrict__ mb)
{
    int i = blockIdx.x*256 + threadIdx.x;   // 0 .. 655359
    if (i < 524288) ob[i] = f2bf(outw[i]);          // L*D*H
    else            mb[i - 524288] = f2bf(mixw[i - 524288]);  // L*H*64
}

// ---------------- kA: LN + grouped in-proj + silu/sigmoid ----------------
__global__ __launch_bounds__(256) void kA(const float* __restrict__ h,
    const float* __restrict__ lng, const float* __restrict__ lnb,
    const float* __restrict__ inw, const float* __restrict__ inb,
    unsigned short* __restrict__ u_ws, unsigned short* __restrict__ g_ws)
{
    const int b  = blockIdx.y;
    const int t0 = blockIdx.x * 8;
    const int P  = min(8, NT - t0);
    const int tid = threadIdx.x;
    const int lane = tid & 63, wvi = tid >> 6;
    __shared__ float yl[8][ND];
    __shared__ float2 part[8][4];
    float hv[8];
    #pragma unroll
    for (int p = 0; p < 8; ++p) {
        if (p < P) {
            float v = h[((size_t)b*NT + t0 + p)*ND + tid];
            hv[p] = v;
            float s = v, s2 = v*v;
            #pragma unroll
            for (int off = 32; off; off >>= 1) {
                s  += __shfl_down(s, off);
                s2 += __shfl_down(s2, off);
            }
            if (lane == 0) part[p][wvi] = make_float2(s, s2);
        }
    }
    __syncthreads();
    const float gsc = lng[tid], gbi = lnb[tid];
    #pragma unroll
    for (int p = 0; p < 8; ++p) {
        if (p < P) {
            float2 a0 = part[p][0], a1 = part[p][1], a2 = part[p][2], a3 = part[p][3];
            float S  = a0.x + a1.x + a2.x + a3.x;
            float S2 = a0.y + a1.y + a2.y + a3.y;
            float mu  = S * (1.0f/ND);
            float var = S2 * (1.0f/ND) - mu*mu;
            float rs  = rsqrtf(var + EPSF);
            yl[p][tid] = (hv[p] - mu) * rs * gsc + gbi;
        } else {
            yl[p][tid] = 0.0f;
        }
    }
    __syncthreads();
    // grouped in-proj: 1024 outputs, each uses 32 inputs of its group
    for (int cc = 0; cc < 4; ++cc) {
        const int c = tid + 256*cc;          // 0..1023 ; c = g*128 + o
        const int g = c >> 7;
        const float4* wr = reinterpret_cast<const float4*>(inw + c*32);
        float w[32];
        #pragma unroll
        for (int i = 0; i < 8; ++i) {
            float4 f = wr[i];
            w[4*i+0]=f.x; w[4*i+1]=f.y; w[4*i+2]=f.z; w[4*i+3]=f.w;
        }
        float acc[8];
        #pragma unroll
        for (int p = 0; p < 8; ++p) acc[p] = 0.0f;
        #pragma unroll
        for (int i = 0; i < 32; ++i) {
            float wv = w[i];
            #pragma unroll
            for (int p = 0; p < 8; ++p) acc[p] = fmaf(wv, yl[p][g*32 + i], acc[p]);
        }
        const float bia = inb[c];
        #pragma unroll
        for (int p = 0; p < 8; ++p) {
            if (p < P) {
                float tv = acc[p] + bia;
                float sg = 1.0f / (1.0f + __expf(-tv));
                size_t base = ((size_t)b*NT + t0 + p)*NH;
                if (c < NH) u_ws[base + c]      = f2bf(tv * sg);   // silu
                else        g_ws[base + c - NH] = f2bf(sg);        // sigmoid(gate)
            }
        }
    }
}

// ------- kB3: symmetric depthwise conv (K=7) + grouped mix (MFMA) + gate -------
// Block: 32 time-rows of one batch, all 512 channels. 4 waves.
__global__ __launch_bounds__(256) void kB3(const unsigned short* __restrict__ u_ws,
    const unsigned short* __restrict__ g_ws, const float* __restrict__ dww,
    const unsigned short* __restrict__ mixw_b, const float* __restrict__ mixb,
    unsigned short* __restrict__ v_ws)
{
    const int b  = blockIdx.y;
    const int t0 = blockIdx.x * 32;
    const int tid = threadIdx.x;
    const int lane = tid & 63, wvid = tid >> 6;
    __shared__ __align__(16) unsigned short ul[38][520];   // halo rows t0-3 .. t0+34
    __shared__ __align__(16) unsigned short uc[32][520];   // conv output (bf16)

    // --- stage u halo tile (16B chunks, coalesced) ---
    for (int idx = tid; idx < 38*64; idx += 256) {
        int r = idx >> 6, c16 = idx & 63;
        int t = t0 - 3 + r;
        u32x4 val = (u32x4){0u,0u,0u,0u};
        if (t >= 0 && t < NT)
            val = *reinterpret_cast<const u32x4*>(u_ws + ((size_t)b*NT + t)*NH + c16*8);
        *reinterpret_cast<u32x4*>(&ul[r][c16*8]) = val;
    }
    __syncthreads();

    // --- symmetrized depthwise conv: thread owns channels 2*tid, 2*tid+1 ---
    {
        const int c0 = 2*tid;
        float wsa[7], wsb[7];
        #pragma unroll
        for (int k = 0; k < 7; ++k) {
            wsa[k] = 0.5f*(dww[c0*7 + k]     + dww[c0*7 + 6-k]);
            wsb[k] = 0.5f*(dww[(c0+1)*7 + k] + dww[(c0+1)*7 + 6-k]);
        }
        for (int p = 0; p < 32; ++p) {
            float s0 = 0.0f, s1 = 0.0f;
            #pragma unroll
            for (int k = 0; k < 7; ++k) {
                unsigned int raw = *reinterpret_cast<const unsigned int*>(&ul[p+k][c0]);
                s0 = fmaf(bf2f((unsigned short)(raw & 0xffffu)), wsa[k], s0);
                s1 = fmaf(bf2f((unsigned short)(raw >> 16)),     wsb[k], s1);
            }
            unsigned int packed = (unsigned)f2bf(s0) | ((unsigned)f2bf(s1) << 16);
            *reinterpret_cast<unsigned int*>(&uc[p][c0]) = packed;
        }
    }
    __syncthreads();

    // --- grouped mix via MFMA 16x16x32 (kC-mirrored issue pattern) + gate ---
    const int r_lo = lane & 15, kb = lane >> 4;
    for (int cb = 0; cb < 4; ++cb) {
        const int combo = wvid*4 + cb;        // 16 combos = 2 row-tiles x 8 groups
        const int rt = combo >> 3, g = combo & 7;
        const int arow = rt*16 + r_lo;
        u32x4 a0 = *reinterpret_cast<const u32x4*>(&uc[arow][g*64 + kb*8]);
        u32x4 a1 = *reinterpret_cast<const u32x4*>(&uc[arow][g*64 + kb*8 + 32]);
        f32x4 acc[4];
        #pragma unroll
        for (int nt = 0; nt < 4; ++nt) acc[nt] = (f32x4){0.f,0.f,0.f,0.f};
        #pragma unroll
        for (int nt = 0; nt < 4; ++nt) {
            const int ocol = g*64 + nt*16 + r_lo;
            u32x4 b0 = *reinterpret_cast<const u32x4*>(mixw_b + (size_t)ocol*64 + kb*8);
            asm("v_mfma_f32_16x16x32_bf16 %0, %1, %2, %0"
                : "+v"(acc[nt]) : "v"(a0), "v"(b0));
        }
        #pragma unroll
        for (int nt = 0; nt < 4; ++nt) {
            const int ocol = g*64 + nt*16 + r_lo;
            u32x4 b1 = *reinterpret_cast<const u32x4*>(mixw_b + (size_t)ocol*64 + kb*8 + 32);
            asm("v_mfma_f32_16x16x32_bf16 %0, %1, %2, %0"
                : "+v"(acc[nt]) : "v"(a1), "v"(b1));
        }
        const int crow0 = rt*16 + kb*4;
        #pragma unroll
        for (int nt = 0; nt < 4; ++nt) {
            const int ocol = g*64 + nt*16 + r_lo;
            const float bia = mixb[ocol];
            #pragma unroll
            for (int r = 0; r < 4; ++r) {
                int trow = t0 + crow0 + r;
                if (trow < NT) {
                    size_t off = ((size_t)b*NT + trow)*NH + ocol;
                    float gate = bf2f(g_ws[off]);
                    v_ws[off] = f2bf((acc[nt][r] + bia) * gate);
                }
            }
        }
    }
}

// ------- kC: out-proj GEMM (bf16 MFMA 16x16x32) + bias + residual -------
__global__ __launch_bounds__(256) void kC(const unsigned short* __restrict__ v_ws,
    const unsigned short* __restrict__ outw_b, const float* __restrict__ outb,
    float* __restrict__ h)
{
    const int d0 = blockIdx.x * 64;            // 4 d-tiles (fastest -> L2 reuse of v rows)
    const int m0 = blockIdx.y * 64;            // 2192 m-tiles
    const int lane = threadIdx.x & 63;
    const int wvi  = threadIdx.x >> 6;
    const int arow = m0 + wvi*16 + (lane & 15);
    const int kof  = (lane >> 4) * 8;
    f32x4 acc[4];
    #pragma unroll
    for (int nt = 0; nt < 4; ++nt) acc[nt] = (f32x4){0.f,0.f,0.f,0.f};
    const unsigned short* abase = v_ws  + (size_t)arow*NH + kof;
    const unsigned short* bbase = outw_b + (size_t)(d0 + (lane & 15))*NH + kof;
    #pragma unroll
    for (int ks = 0; ks < 16; ++ks) {
        u32x4 af = *reinterpret_cast<const u32x4*>(abase + ks*32);
        #pragma unroll
        for (int nt = 0; nt < 4; ++nt) {
            u32x4 bfv = *reinterpret_cast<const u32x4*>(bbase + (size_t)nt*16*NH + ks*32);
            asm("v_mfma_f32_16x16x32_bf16 %0, %1, %2, %0"
                : "+v"(acc[nt]) : "v"(af), "v"(bfv));
        }
    }
    const int crow = m0 + wvi*16 + (lane >> 4)*4;
    #pragma unroll
    for (int nt = 0; nt < 4; ++nt) {
        int d = d0 + nt*16 + (lane & 15);
        float ob = outb[d];
        #pragma unroll
        for (int r = 0; r < 4; ++r) {
            size_t off = (size_t)(crow + r)*ND + d;
            h[off] += acc[nt][r] + ob;
        }
    }
}

// ---------------- final layernorm (in place) ----------------
__global__ __launch_bounds__(256) void kLN(float* __restrict__ h,
    const float* __restrict__ g, const float* __restrict__ bb)
{
    const int row = blockIdx.x;
    const int tid = threadIdx.x;
    const int lane = tid & 63, wvi = tid >> 6;
    __shared__ float2 part[4];
    float v = h[(size_t)row*ND + tid];
    float s = v, s2 = v*v;
    #pragma unroll
    for (int off = 32; off; off >>= 1) { s += __shfl_down(s, off); s2 += __shfl_down(s2, off); }
    if (lane == 0) part[wvi] = make_float2(s, s2);
    __syncthreads();
    float2 a0 = part[0], a1 = part[1], a2 = part[2], a3 = part[3];
    float S  = a0.x+a1.x+a2.x+a3.x;
    float S2 = a0.y+a1.y+a2.y+a3.y;
    float mu  = S*(1.0f/ND);
    float var = S2*(1.0f/ND) - mu*mu;
    float rs  = rsqrtf(var + EPSF);
    h[(size_t)row*ND + tid] = (v - mu)*rs*g[tid] + bb[tid];
}

extern "C" void kernel_launch(void* const* d_in, const int* in_sizes, int n_in,
                              void* d_out, int out_size, void* d_ws, size_t ws_size,
                              hipStream_t stream)
{
    const float* x    = (const float*)d_in[0];
    const float* w_in = (const float*)d_in[1];
    const float* b_in = (const float*)d_in[2];
    const float* pos  = (const float*)d_in[3];
    const float* ln_g = (const float*)d_in[4];
    const float* ln_b = (const float*)d_in[5];
    const float* inw  = (const float*)d_in[6];
    const float* inb  = (const float*)d_in[7];
    const float* dww  = (const float*)d_in[8];
    const float* mixw = (const float*)d_in[9];
    const float* mixb = (const float*)d_in[10];
    const float* outw = (const float*)d_in[11];
    const float* outb = (const float*)d_in[12];
    const float* olng = (const float*)d_in[13];
    const float* olnb = (const float*)d_in[14];
    float* h = (float*)d_out;

    const size_t UB = (size_t)NPOS * NH;          // 71,827,456 elems
    unsigned short* u_ws   = (unsigned short*)d_ws;
    unsigned short* g_ws   = u_ws + UB;
    unsigned short* v_ws   = g_ws + UB;
    unsigned short* outw_b = v_ws + UB;           // L*D*H = 524288 bf16
    unsigned short* mixw_b = outw_b + 524288;     // L*H*64 = 131072 bf16

    k_init<<<NPOS, 256, 0, stream>>>(x, w_in, b_in, pos, h);
    k_prep<<<2560, 256, 0, stream>>>(outw, mixw, outw_b, mixw_b);
    for (int l = 0; l < 4; ++l) {
        kA<<<dim3(35, NB), 256, 0, stream>>>(h, ln_g + l*ND, ln_b + l*ND,
            inw + (size_t)l*NHH*32, inb + l*NHH, u_ws, g_ws);
        kB3<<<dim3(9, NB), 256, 0, stream>>>(u_ws, g_ws, dww + l*NH*7,
            mixw_b + (size_t)l*NH*64, mixb + l*NH, v_ws);
        kC<<<dim3(4, NPOS/64), 256, 0, stream>>>(v_ws, outw_b + (size_t)l*ND*NH,
            outb + l*ND, h);
    }
    kLN<<<NPOS, 256, 0, stream>>>(h, olng, olnb);
}

// Round 4
// 3272.025 us; speedup vs baseline: 8.9379x; 2.1676x over previous
//
#include <hip/hip_runtime.h>

#define NB 512
#define NT 274
#define ND 256
#define NH 512
#define NHH 1024
#define NPOS (NB*NT)
#define EPSF 1e-5f

typedef float f32x4 __attribute__((ext_vector_type(4)));
typedef unsigned int u32x4 __attribute__((ext_vector_type(4)));

__device__ __forceinline__ float bf2f(unsigned short s) {
    unsigned int u = ((unsigned int)s) << 16;
    float f; __builtin_memcpy(&f, &u, 4); return f;
}
__device__ __forceinline__ unsigned short f2bf(float f) {
    unsigned int u; __builtin_memcpy(&u, &f, 4);
    unsigned int r = u + 0x7FFFu + ((u >> 16) & 1u);   // round-to-nearest-even
    return (unsigned short)(r >> 16);
}

// ---------------- init: h = x[:,:,None]*w_in + b_in + pos ----------------
__global__ __launch_bounds__(256) void k_init(const float* __restrict__ x,
    const float* __restrict__ w_in, const float* __restrict__ b_in,
    const float* __restrict__ pos, float* __restrict__ h)
{
    int row = blockIdx.x;              // 0..NPOS-1  (b*NT + t)
    int d = threadIdx.x;
    int t = row % NT;
    float xv = x[row];
    h[(size_t)row*ND + d] = fmaf(xv, w_in[d], b_in[d] + pos[t*ND + d]);
}

// ------- prep: outw/mixw/inw (f32) -> bf16 -------
__global__ __launch_bounds__(256) void k_prep(const float* __restrict__ outw,
    const float* __restrict__ mixw, const float* __restrict__ inw,
    unsigned short* __restrict__ ob, unsigned short* __restrict__ mb,
    unsigned short* __restrict__ iwb)
{
    int i = blockIdx.x*256 + threadIdx.x;   // 0 .. 786431
    if (i < 524288)      ob[i] = f2bf(outw[i]);               // L*D*H
    else if (i < 655360) mb[i - 524288] = f2bf(mixw[i - 524288]);   // L*H*64
    else                 iwb[i - 655360] = f2bf(inw[i - 655360]);   // L*1024*32
}

// ------- kA2: LN + grouped in-proj (MFMA 16x16x32, K=32) + silu/sigmoid -------
// Block: 32 time-rows of one batch. 4 waves.
__global__ __launch_bounds__(256) void kA2(const float* __restrict__ h,
    const float* __restrict__ lng, const float* __restrict__ lnb,
    const unsigned short* __restrict__ inw_b, const float* __restrict__ inb,
    unsigned short* __restrict__ u_ws, unsigned short* __restrict__ g_ws)
{
    const int b  = blockIdx.y;
    const int t0 = blockIdx.x * 32;
    const int tid = threadIdx.x;
    const int lane = tid & 63, wvid = tid >> 6;
    __shared__ __align__(16) unsigned short yl[32][264];  // y bf16, row stride 528B (16B-mult)
    __shared__ float s_lng[ND], s_lnb[ND];
    __shared__ float s_inb[NHH];

    // stage small params
    s_lng[tid] = lng[tid];
    s_lnb[tid] = lnb[tid];
    #pragma unroll
    for (int q = 0; q < 4; ++q) s_inb[tid + 256*q] = inb[tid + 256*q];

    // --- LN: thread owns row r = tid>>3, channels c0 = (tid&7)*32 ---
    {
        const int r  = tid >> 3;
        const int c0 = (tid & 7) * 32;
        const int trow = t0 + r;
        float vals[32];
        if (trow < NT) {
            const float4* hp = reinterpret_cast<const float4*>(
                h + ((size_t)b*NT + trow)*ND + c0);
            #pragma unroll
            for (int j = 0; j < 8; ++j) {
                float4 f = hp[j];
                vals[4*j+0]=f.x; vals[4*j+1]=f.y; vals[4*j+2]=f.z; vals[4*j+3]=f.w;
            }
        } else {
            #pragma unroll
            for (int j = 0; j < 32; ++j) vals[j] = 0.0f;
        }
        float s = 0.f, s2 = 0.f;
        #pragma unroll
        for (int j = 0; j < 32; ++j) { s += vals[j]; s2 += vals[j]*vals[j]; }
        #pragma unroll
        for (int off = 1; off < 8; off <<= 1) {   // 8 lanes per row, groups 8-aligned
            s  += __shfl_xor(s, off);
            s2 += __shfl_xor(s2, off);
        }
        float mu  = s * (1.0f/ND);
        float var = s2 * (1.0f/ND) - mu*mu;
        float rs  = rsqrtf(var + EPSF);
        __syncthreads();   // s_lng/s_lnb ready
        #pragma unroll
        for (int j = 0; j < 16; ++j) {
            int c = c0 + 2*j;
            float y0 = (vals[2*j]   - mu) * rs * s_lng[c]   + s_lnb[c];
            float y1 = (vals[2*j+1] - mu) * rs * s_lng[c+1] + s_lnb[c+1];
            unsigned int packed = (unsigned)f2bf(y0) | ((unsigned)f2bf(y1) << 16);
            *reinterpret_cast<unsigned int*>(&yl[r][c]) = packed;
        }
    }
    __syncthreads();

    // --- grouped in-proj via MFMA 16x16x32 (K=32 = one chunk) ---
    const int r_lo = lane & 15, kb = lane >> 4;
    for (int cb = 0; cb < 4; ++cb) {
        const int combo = wvid*4 + cb;        // 16 combos = 2 row-tiles x 8 groups
        const int rt = combo >> 3, g = combo & 7;
        const int arow = rt*16 + r_lo;
        u32x4 a = *reinterpret_cast<const u32x4*>(&yl[arow][g*32 + kb*8]);
        f32x4 acc[8];
        #pragma unroll
        for (int nt = 0; nt < 8; ++nt) acc[nt] = (f32x4){0.f,0.f,0.f,0.f};
        #pragma unroll
        for (int nt = 0; nt < 8; ++nt) {
            const int ocol = g*128 + nt*16 + r_lo;
            u32x4 bf = *reinterpret_cast<const u32x4*>(inw_b + (size_t)ocol*32 + kb*8);
            asm("v_mfma_f32_16x16x32_bf16 %0, %1, %2, %0"
                : "+v"(acc[nt]) : "v"(a), "v"(bf));
        }
        const int crow0 = rt*16 + kb*4;
        #pragma unroll
        for (int nt = 0; nt < 8; ++nt) {
            const int ocol = g*128 + nt*16 + r_lo;
            const float bia = s_inb[ocol];
            #pragma unroll
            for (int r = 0; r < 4; ++r) {
                int trow = t0 + crow0 + r;
                if (trow < NT) {
                    float tv = acc[nt][r] + bia;
                    float sg = 1.0f / (1.0f + __expf(-tv));
                    size_t base = ((size_t)b*NT + trow)*NH;
                    if (ocol < NH) u_ws[base + ocol]      = f2bf(tv * sg);
                    else           g_ws[base + ocol - NH] = f2bf(sg);
                }
            }
        }
    }
}

// ------- kB3: symmetric depthwise conv (K=7) + grouped mix (MFMA) + gate -------
__global__ __launch_bounds__(256) void kB3(const unsigned short* __restrict__ u_ws,
    const unsigned short* __restrict__ g_ws, const float* __restrict__ dww,
    const unsigned short* __restrict__ mixw_b, const float* __restrict__ mixb,
    unsigned short* __restrict__ v_ws)
{
    const int b  = blockIdx.y;
    const int t0 = blockIdx.x * 32;
    const int tid = threadIdx.x;
    const int lane = tid & 63, wvid = tid >> 6;
    __shared__ __align__(16) unsigned short ul[38][520];   // halo rows t0-3 .. t0+34
    __shared__ __align__(16) unsigned short uc[32][520];   // conv output (bf16)

    for (int idx = tid; idx < 38*64; idx += 256) {
        int r = idx >> 6, c16 = idx & 63;
        int t = t0 - 3 + r;
        u32x4 val = (u32x4){0u,0u,0u,0u};
        if (t >= 0 && t < NT)
            val = *reinterpret_cast<const u32x4*>(u_ws + ((size_t)b*NT + t)*NH + c16*8);
        *reinterpret_cast<u32x4*>(&ul[r][c16*8]) = val;
    }
    __syncthreads();

    {
        const int c0 = 2*tid;
        float wsa[7], wsb[7];
        #pragma unroll
        for (int k = 0; k < 7; ++k) {
            wsa[k] = 0.5f*(dww[c0*7 + k]     + dww[c0*7 + 6-k]);
            wsb[k] = 0.5f*(dww[(c0+1)*7 + k] + dww[(c0+1)*7 + 6-k]);
        }
        for (int p = 0; p < 32; ++p) {
            float s0 = 0.0f, s1 = 0.0f;
            #pragma unroll
            for (int k = 0; k < 7; ++k) {
                unsigned int raw = *reinterpret_cast<const unsigned int*>(&ul[p+k][c0]);
                s0 = fmaf(bf2f((unsigned short)(raw & 0xffffu)), wsa[k], s0);
                s1 = fmaf(bf2f((unsigned short)(raw >> 16)),     wsb[k], s1);
            }
            unsigned int packed = (unsigned)f2bf(s0) | ((unsigned)f2bf(s1) << 16);
            *reinterpret_cast<unsigned int*>(&uc[p][c0]) = packed;
        }
    }
    __syncthreads();

    const int r_lo = lane & 15, kb = lane >> 4;
    for (int cb = 0; cb < 4; ++cb) {
        const int combo = wvid*4 + cb;        // 16 combos = 2 row-tiles x 8 groups
        const int rt = combo >> 3, g = combo & 7;
        const int arow = rt*16 + r_lo;
        u32x4 a0 = *reinterpret_cast<const u32x4*>(&uc[arow][g*64 + kb*8]);
        u32x4 a1 = *reinterpret_cast<const u32x4*>(&uc[arow][g*64 + kb*8 + 32]);
        f32x4 acc[4];
        #pragma unroll
        for (int nt = 0; nt < 4; ++nt) acc[nt] = (f32x4){0.f,0.f,0.f,0.f};
        #pragma unroll
        for (int nt = 0; nt < 4; ++nt) {
            const int ocol = g*64 + nt*16 + r_lo;
            u32x4 b0 = *reinterpret_cast<const u32x4*>(mixw_b + (size_t)ocol*64 + kb*8);
            asm("v_mfma_f32_16x16x32_bf16 %0, %1, %2, %0"
                : "+v"(acc[nt]) : "v"(a0), "v"(b0));
        }
        #pragma unroll
        for (int nt = 0; nt < 4; ++nt) {
            const int ocol = g*64 + nt*16 + r_lo;
            u32x4 b1 = *reinterpret_cast<const u32x4*>(mixw_b + (size_t)ocol*64 + kb*8 + 32);
            asm("v_mfma_f32_16x16x32_bf16 %0, %1, %2, %0"
                : "+v"(acc[nt]) : "v"(a1), "v"(b1));
        }
        const int crow0 = rt*16 + kb*4;
        #pragma unroll
        for (int nt = 0; nt < 4; ++nt) {
            const int ocol = g*64 + nt*16 + r_lo;
            const float bia = mixb[ocol];
            #pragma unroll
            for (int r = 0; r < 4; ++r) {
                int trow = t0 + crow0 + r;
                if (trow < NT) {
                    size_t off = ((size_t)b*NT + trow)*NH + ocol;
                    float gate = bf2f(g_ws[off]);
                    v_ws[off] = f2bf((acc[nt][r] + bia) * gate);
                }
            }
        }
    }
}

// ------- kC: out-proj GEMM (bf16 MFMA 16x16x32) + bias + residual -------
__global__ __launch_bounds__(256) void kC(const unsigned short* __restrict__ v_ws,
    const unsigned short* __restrict__ outw_b, const float* __restrict__ outb,
    float* __restrict__ h)
{
    const int d0 = blockIdx.x * 64;            // 4 d-tiles (fastest -> L2 reuse of v rows)
    const int m0 = blockIdx.y * 64;            // 2192 m-tiles
    const int lane = threadIdx.x & 63;
    const int wvi  = threadIdx.x >> 6;
    const int arow = m0 + wvi*16 + (lane & 15);
    const int kof  = (lane >> 4) * 8;
    f32x4 acc[4];
    #pragma unroll
    for (int nt = 0; nt < 4; ++nt) acc[nt] = (f32x4){0.f,0.f,0.f,0.f};
    const unsigned short* abase = v_ws  + (size_t)arow*NH + kof;
    const unsigned short* bbase = outw_b + (size_t)(d0 + (lane & 15))*NH + kof;
    #pragma unroll
    for (int ks = 0; ks < 16; ++ks) {
        u32x4 af = *reinterpret_cast<const u32x4*>(abase + ks*32);
        #pragma unroll
        for (int nt = 0; nt < 4; ++nt) {
            u32x4 bfv = *reinterpret_cast<const u32x4*>(bbase + (size_t)nt*16*NH + ks*32);
            asm("v_mfma_f32_16x16x32_bf16 %0, %1, %2, %0"
                : "+v"(acc[nt]) : "v"(af), "v"(bfv));
        }
    }
    const int crow = m0 + wvi*16 + (lane >> 4)*4;
    #pragma unroll
    for (int nt = 0; nt < 4; ++nt) {
        int d = d0 + nt*16 + (lane & 15);
        float ob = outb[d];
        #pragma unroll
        for (int r = 0; r < 4; ++r) {
            size_t off = (size_t)(crow + r)*ND + d;
            h[off] += acc[nt][r] + ob;
        }
    }
}

// ---------------- final layernorm (in place) ----------------
__global__ __launch_bounds__(256) void kLN(float* __restrict__ h,
    const float* __restrict__ g, const float* __restrict__ bb)
{
    const int row = blockIdx.x;
    const int tid = threadIdx.x;
    const int lane = tid & 63, wvi = tid >> 6;
    __shared__ float2 part[4];
    float v = h[(size_t)row*ND + tid];
    float s = v, s2 = v*v;
    #pragma unroll
    for (int off = 32; off; off >>= 1) { s += __shfl_down(s, off); s2 += __shfl_down(s2, off); }
    if (lane == 0) part[wvi] = make_float2(s, s2);
    __syncthreads();
    float2 a0 = part[0], a1 = part[1], a2 = part[2], a3 = part[3];
    float S  = a0.x+a1.x+a2.x+a3.x;
    float S2 = a0.y+a1.y+a2.y+a3.y;
    float mu  = S*(1.0f/ND);
    float var = S2*(1.0f/ND) - mu*mu;
    float rs  = rsqrtf(var + EPSF);
    h[(size_t)row*ND + tid] = (v - mu)*rs*g[tid] + bb[tid];
}

extern "C" void kernel_launch(void* const* d_in, const int* in_sizes, int n_in,
                              void* d_out, int out_size, void* d_ws, size_t ws_size,
                              hipStream_t stream)
{
    const float* x    = (const float*)d_in[0];
    const float* w_in = (const float*)d_in[1];
    const float* b_in = (const float*)d_in[2];
    const float* pos  = (const float*)d_in[3];
    const float* ln_g = (const float*)d_in[4];
    const float* ln_b = (const float*)d_in[5];
    const float* inw  = (const float*)d_in[6];
    const float* inb  = (const float*)d_in[7];
    const float* dww  = (const float*)d_in[8];
    const float* mixw = (const float*)d_in[9];
    const float* mixb = (const float*)d_in[10];
    const float* outw = (const float*)d_in[11];
    const float* outb = (const float*)d_in[12];
    const float* olng = (const float*)d_in[13];
    const float* olnb = (const float*)d_in[14];
    float* h = (float*)d_out;

    const size_t UB = (size_t)NPOS * NH;          // 71,827,456 elems
    unsigned short* u_ws   = (unsigned short*)d_ws;
    unsigned short* g_ws   = u_ws + UB;
    unsigned short* v_ws   = g_ws + UB;
    unsigned short* outw_b = v_ws + UB;           // L*D*H = 524288 bf16
    unsigned short* mixw_b = outw_b + 524288;     // L*H*64 = 131072 bf16
    unsigned short* inw_b  = mixw_b + 131072;     // L*1024*32 = 131072 bf16

    k_init<<<NPOS, 256, 0, stream>>>(x, w_in, b_in, pos, h);
    k_prep<<<3072, 256, 0, stream>>>(outw, mixw, inw, outw_b, mixw_b, inw_b);
    for (int l = 0; l < 4; ++l) {
        kA2<<<dim3(9, NB), 256, 0, stream>>>(h, ln_g + l*ND, ln_b + l*ND,
            inw_b + (size_t)l*NHH*32, inb + l*NHH, u_ws, g_ws);
        kB3<<<dim3(9, NB), 256, 0, stream>>>(u_ws, g_ws, dww + l*NH*7,
            mixw_b + (size_t)l*NH*64, mixb + l*NH, v_ws);
        kC<<<dim3(4, NPOS/64), 256, 0, stream>>>(v_ws, outw_b + (size_t)l*ND*NH,
            outb + l*ND, h);
    }
    kLN<<<NPOS, 256, 0, stream>>>(h, olng, olnb);
}

// Round 5
// 2776.412 us; speedup vs baseline: 10.5334x; 1.1785x over previous
//
#include <hip/hip_runtime.h>

#define NB 512
#define NT 274
#define ND 256
#define NH 512
#define NHH 1024
#define NPOS (NB*NT)
#define EPSF 1e-5f
#define TILE 16
#define HALO 22           // TILE + 6
#define YROWS 32
#define YST 264           // y row stride (elems), 528B = 132 dw == 4 mod 32
#define UST 520           // u/uc/v row stride, 1040B = 260 dw == 4 mod 32
#define GST 516           // gate row stride (scalar access only)

typedef float f32x4 __attribute__((ext_vector_type(4)));
typedef unsigned int u32x4 __attribute__((ext_vector_type(4)));
typedef unsigned int u32x2 __attribute__((ext_vector_type(2)));

__device__ __forceinline__ float bf2f(unsigned short s) {
    unsigned int u = ((unsigned int)s) << 16;
    float f; __builtin_memcpy(&f, &u, 4); return f;
}
__device__ __forceinline__ unsigned short f2bf(float f) {
    unsigned int u; __builtin_memcpy(&u, &f, 4);
    unsigned int r = u + 0x7FFFu + ((u >> 16) & 1u);   // round-to-nearest-even
    return (unsigned short)(r >> 16);
}

// ---------------- init: h = x[:,:,None]*w_in + b_in + pos ----------------
__global__ __launch_bounds__(256) void k_init(const float* __restrict__ x,
    const float* __restrict__ w_in, const float* __restrict__ b_in,
    const float* __restrict__ pos, float* __restrict__ h)
{
    int row = blockIdx.x;              // 0..NPOS-1  (b*NT + t)
    int d = threadIdx.x;
    int t = row % NT;
    float xv = x[row];
    h[(size_t)row*ND + d] = fmaf(xv, w_in[d], b_in[d] + pos[t*ND + d]);
}

// ------- prep: outw/mixw/inw (f32) -> bf16 -------
__global__ __launch_bounds__(256) void k_prep(const float* __restrict__ outw,
    const float* __restrict__ mixw, const float* __restrict__ inw,
    unsigned short* __restrict__ ob, unsigned short* __restrict__ mb,
    unsigned short* __restrict__ iwb)
{
    int i = blockIdx.x*256 + threadIdx.x;   // 0 .. 786431
    if (i < 524288)      ob[i] = f2bf(outw[i]);                     // L*D*H
    else if (i < 655360) mb[i - 524288] = f2bf(mixw[i - 524288]);   // L*H*64
    else                 iwb[i - 655360] = f2bf(inw[i - 655360]);   // L*1024*32
}

// ======= kL: whole layer fused =======
// Block: 16 central time-rows (halo 22) of one batch. 4 waves.
__global__ __launch_bounds__(256) void kL(const float* __restrict__ hin,
    float* __restrict__ hout,
    const float* __restrict__ lng, const float* __restrict__ lnb,
    const unsigned short* __restrict__ inw_b, const float* __restrict__ inb,
    const float* __restrict__ dww,
    const unsigned short* __restrict__ mixw_b, const float* __restrict__ mixb,
    const unsigned short* __restrict__ outw_b, const float* __restrict__ outb)
{
    const int b   = blockIdx.y;
    const int t0  = blockIdx.x * TILE;
    const int tid = threadIdx.x;
    const int lane = tid & 63, wvid = tid >> 6;
    const int r_lo = lane & 15, kb = lane >> 4;

    __shared__ __align__(16) unsigned short s_m[YROWS*YST];  // y (32xYST) -> uc (16xUST)
    __shared__ __align__(16) unsigned short s_u[HALO*UST];   // u (22xUST) -> v (16xUST)
    __shared__ __align__(16) unsigned short s_g[TILE*GST];   // gate
    __shared__ float s_par[2304]; // lng[256] lnb[256] inb[1024] mixb[512] outb[256]

    // --- stage params ---
    for (int i = tid; i < 2304; i += 256) {
        float v;
        if (i < 256)       v = lng[i];
        else if (i < 512)  v = lnb[i-256];
        else if (i < 1536) v = inb[i-512];
        else if (i < 2048) v = mixb[i-1536];
        else               v = outb[i-2048];
        s_par[i] = v;
    }

    // --- P0: load h rows (halo) into regs ---
    float vals[2][16];
    int rr[2]; bool vld[2];
    #pragma unroll
    for (int pass = 0; pass < 2; ++pass) {
        int r = (tid >> 4) + 16*pass;       // 0..31
        int t = t0 - 3 + r;
        rr[pass] = r;
        vld[pass] = (r < HALO) && (t >= 0) && (t < NT);
        if (vld[pass]) {
            const float4* hp = reinterpret_cast<const float4*>(hin + ((size_t)b*NT + t)*ND);
            #pragma unroll
            for (int j = 0; j < 4; ++j) {
                float4 f = hp[(tid & 15) + 16*j];   // cols j*64 + (tid&15)*4 .. +3
                vals[pass][4*j+0]=f.x; vals[pass][4*j+1]=f.y;
                vals[pass][4*j+2]=f.z; vals[pass][4*j+3]=f.w;
            }
        } else {
            #pragma unroll
            for (int j = 0; j < 16; ++j) vals[pass][j] = 0.0f;
        }
    }
    __syncthreads();   // s_par ready

    // --- LN -> y (bf16 in s_m) ---
    #pragma unroll
    for (int pass = 0; pass < 2; ++pass) {
        int r = rr[pass];
        if (vld[pass]) {
            float s = 0.f, s2 = 0.f;
            #pragma unroll
            for (int j = 0; j < 16; ++j) { s += vals[pass][j]; s2 += vals[pass][j]*vals[pass][j]; }
            #pragma unroll
            for (int off = 1; off < 16; off <<= 1) {   // 16 lanes per row, 16-aligned
                s  += __shfl_xor(s, off);
                s2 += __shfl_xor(s2, off);
            }
            float mu  = s * (1.0f/ND);
            float var = s2 * (1.0f/ND) - mu*mu;
            float rs  = rsqrtf(var + EPSF);
            #pragma unroll
            for (int j = 0; j < 4; ++j) {
                int cb0 = j*64 + (tid & 15)*4;
                u32x2 pk;
                float y0 = (vals[pass][4*j+0] - mu)*rs*s_par[cb0+0] + s_par[256+cb0+0];
                float y1 = (vals[pass][4*j+1] - mu)*rs*s_par[cb0+1] + s_par[256+cb0+1];
                float y2 = (vals[pass][4*j+2] - mu)*rs*s_par[cb0+2] + s_par[256+cb0+2];
                float y3 = (vals[pass][4*j+3] - mu)*rs*s_par[cb0+3] + s_par[256+cb0+3];
                pk[0] = (unsigned)f2bf(y0) | ((unsigned)f2bf(y1) << 16);
                pk[1] = (unsigned)f2bf(y2) | ((unsigned)f2bf(y3) << 16);
                *reinterpret_cast<u32x2*>(&s_m[r*YST + cb0]) = pk;
            }
        } else {
            #pragma unroll
            for (int j = 0; j < 4; ++j) {
                int cb0 = j*64 + (tid & 15)*4;
                *reinterpret_cast<u32x2*>(&s_m[r*YST + cb0]) = (u32x2){0u,0u};
            }
        }
    }
    __syncthreads();

    // --- P1: grouped in-proj (MFMA, K=32) -> u (silu) + gate (sigmoid) ---
    for (int cb = 0; cb < 4; ++cb) {
        const int combo = wvid + 4*cb;       // 0..15 = rt*8 + g
        const int rt = combo >> 3, g = combo & 7;
        u32x4 a = *reinterpret_cast<const u32x4*>(&s_m[(rt*16 + r_lo)*YST + g*32 + kb*8]);
        f32x4 acc[8];
        #pragma unroll
        for (int nt = 0; nt < 8; ++nt) acc[nt] = (f32x4){0.f,0.f,0.f,0.f};
        #pragma unroll
        for (int nt = 0; nt < 8; ++nt) {
            u32x4 bf = *reinterpret_cast<const u32x4*>(
                inw_b + (size_t)(g*128 + nt*16 + r_lo)*32 + kb*8);
            asm("v_mfma_f32_16x16x32_bf16 %0, %1, %2, %0"
                : "+v"(acc[nt]) : "v"(a), "v"(bf));
        }
        const int hr0 = rt*16 + kb*4;
        if (g < 4) {        // u channels
            #pragma unroll
            for (int nt = 0; nt < 8; ++nt) {
                const int ocol = g*128 + nt*16 + r_lo;
                const float bia = s_par[512 + ocol];
                #pragma unroll
                for (int r = 0; r < 4; ++r) {
                    int hr = hr0 + r;
                    if (hr < HALO) {
                        float tv = acc[nt][r] + bia;
                        float sg = 1.0f / (1.0f + __expf(-tv));
                        s_u[hr*UST + ocol] = f2bf(tv * sg);
                    }
                }
            }
        } else {            // gate channels
            #pragma unroll
            for (int nt = 0; nt < 8; ++nt) {
                const int ocol = g*128 + nt*16 + r_lo;     // 512..1023
                const float bia = s_par[512 + ocol];
                #pragma unroll
                for (int r = 0; r < 4; ++r) {
                    int cr = hr0 + r - 3;
                    if (cr >= 0 && cr < TILE) {
                        float tv = acc[nt][r] + bia;
                        s_g[cr*GST + (ocol - 512)] = f2bf(1.0f / (1.0f + __expf(-tv)));
                    }
                }
            }
        }
    }
    __syncthreads();

    // --- P2: symmetric depthwise conv -> uc (into s_m) ---
    #pragma unroll
    for (int cc = 0; cc < 2; ++cc) {
        const int c = tid + 256*cc;
        float ws[7];
        #pragma unroll
        for (int k = 0; k < 7; ++k)
            ws[k] = 0.5f*(dww[c*7 + k] + dww[c*7 + 6 - k]);
        float uv[HALO];
        #pragma unroll
        for (int hr = 0; hr < HALO; ++hr) {
            int t = t0 - 3 + hr;
            uv[hr] = (t >= 0 && t < NT) ? bf2f(s_u[hr*UST + c]) : 0.0f;
        }
        #pragma unroll
        for (int cr = 0; cr < TILE; ++cr) {
            float s = 0.0f;
            #pragma unroll
            for (int k = 0; k < 7; ++k) s = fmaf(ws[k], uv[cr + k], s);
            s_m[cr*UST + c] = f2bf(s);
        }
    }
    __syncthreads();

    // --- P3: grouped mix (MFMA, K=64) + gate -> v (into s_u) ---
    for (int cb = 0; cb < 2; ++cb) {
        const int g = wvid + 4*cb;           // 0..7
        u32x4 a0 = *reinterpret_cast<const u32x4*>(&s_m[r_lo*UST + g*64 + kb*8]);
        u32x4 a1 = *reinterpret_cast<const u32x4*>(&s_m[r_lo*UST + g*64 + 32 + kb*8]);
        f32x4 acc[4];
        #pragma unroll
        for (int nt = 0; nt < 4; ++nt) acc[nt] = (f32x4){0.f,0.f,0.f,0.f};
        #pragma unroll
        for (int nt = 0; nt < 4; ++nt) {
            u32x4 b0 = *reinterpret_cast<const u32x4*>(
                mixw_b + (size_t)(g*64 + nt*16 + r_lo)*64 + kb*8);
            asm("v_mfma_f32_16x16x32_bf16 %0, %1, %2, %0"
                : "+v"(acc[nt]) : "v"(a0), "v"(b0));
        }
        #pragma unroll
        for (int nt = 0; nt < 4; ++nt) {
            u32x4 b1 = *reinterpret_cast<const u32x4*>(
                mixw_b + (size_t)(g*64 + nt*16 + r_lo)*64 + 32 + kb*8);
            asm("v_mfma_f32_16x16x32_bf16 %0, %1, %2, %0"
                : "+v"(acc[nt]) : "v"(a1), "v"(b1));
        }
        #pragma unroll
        for (int nt = 0; nt < 4; ++nt) {
            const int ocol = g*64 + nt*16 + r_lo;
            const float bia = s_par[1536 + ocol];
            #pragma unroll
            for (int r = 0; r < 4; ++r) {
                const int cr = kb*4 + r;
                float gate = bf2f(s_g[cr*GST + ocol]);
                s_u[cr*UST + ocol] = f2bf((acc[nt][r] + bia) * gate);
            }
        }
    }
    __syncthreads();

    // --- P4: out-proj (MFMA, K=512) + bias + residual -> hout ---
    f32x4 acc4[4];
    #pragma unroll
    for (int c4 = 0; c4 < 4; ++c4) acc4[c4] = (f32x4){0.f,0.f,0.f,0.f};
    #pragma unroll
    for (int ks = 0; ks < 16; ++ks) {
        u32x4 a = *reinterpret_cast<const u32x4*>(&s_u[r_lo*UST + ks*32 + kb*8]);
        #pragma unroll
        for (int c4 = 0; c4 < 4; ++c4) {
            const int ocol = (wvid*4 + c4)*16 + r_lo;
            u32x4 bf = *reinterpret_cast<const u32x4*>(
                outw_b + (size_t)ocol*NH + ks*32 + kb*8);
            asm("v_mfma_f32_16x16x32_bf16 %0, %1, %2, %0"
                : "+v"(acc4[c4]) : "v"(a), "v"(bf));
        }
    }
    #pragma unroll
    for (int c4 = 0; c4 < 4; ++c4) {
        const int d = (wvid*4 + c4)*16 + r_lo;
        const float ob = s_par[2048 + d];
        #pragma unroll
        for (int r = 0; r < 4; ++r) {
            const int cr = kb*4 + r;
            const int t = t0 + cr;
            if (t < NT) {
                size_t off = ((size_t)b*NT + t)*ND + d;
                hout[off] = hin[off] + acc4[c4][r] + ob;
            }
        }
    }
}

// ---------------- final layernorm (in place) ----------------
__global__ __launch_bounds__(256) void kLN(float* __restrict__ h,
    const float* __restrict__ g, const float* __restrict__ bb)
{
    const int row = blockIdx.x;
    const int tid = threadIdx.x;
    const int lane = tid & 63, wvi = tid >> 6;
    __shared__ float2 part[4];
    float v = h[(size_t)row*ND + tid];
    float s = v, s2 = v*v;
    #pragma unroll
    for (int off = 32; off; off >>= 1) { s += __shfl_down(s, off); s2 += __shfl_down(s2, off); }
    if (lane == 0) part[wvi] = make_float2(s, s2);
    __syncthreads();
    float2 a0 = part[0], a1 = part[1], a2 = part[2], a3 = part[3];
    float S  = a0.x+a1.x+a2.x+a3.x;
    float S2 = a0.y+a1.y+a2.y+a3.y;
    float mu  = S*(1.0f/ND);
    float var = S2*(1.0f/ND) - mu*mu;
    float rs  = rsqrtf(var + EPSF);
    h[(size_t)row*ND + tid] = (v - mu)*rs*g[tid] + bb[tid];
}

extern "C" void kernel_launch(void* const* d_in, const int* in_sizes, int n_in,
                              void* d_out, int out_size, void* d_ws, size_t ws_size,
                              hipStream_t stream)
{
    const float* x    = (const float*)d_in[0];
    const float* w_in = (const float*)d_in[1];
    const float* b_in = (const float*)d_in[2];
    const float* pos  = (const float*)d_in[3];
    const float* ln_g = (const float*)d_in[4];
    const float* ln_b = (const float*)d_in[5];
    const float* inw  = (const float*)d_in[6];
    const float* inb  = (const float*)d_in[7];
    const float* dww  = (const float*)d_in[8];
    const float* mixw = (const float*)d_in[9];
    const float* mixb = (const float*)d_in[10];
    const float* outw = (const float*)d_in[11];
    const float* outb = (const float*)d_in[12];
    const float* olng = (const float*)d_in[13];
    const float* olnb = (const float*)d_in[14];

    float* hA = (float*)d_out;                       // h ping
    float* hB = (float*)d_ws;                        // h pong (NPOS*ND f32)
    unsigned short* outw_b = (unsigned short*)((char*)d_ws + (size_t)NPOS*ND*4);
    unsigned short* mixw_b = outw_b + 524288;        // L*D*H
    unsigned short* inw_b  = mixw_b + 131072;        // L*H*64 ; then L*1024*32

    k_init<<<NPOS, 256, 0, stream>>>(x, w_in, b_in, pos, hA);
    k_prep<<<3072, 256, 0, stream>>>(outw, mixw, inw, outw_b, mixw_b, inw_b);
    for (int l = 0; l < 4; ++l) {
        const float* src = (l & 1) ? hB : hA;
        float*       dst = (l & 1) ? hA : hB;
        kL<<<dim3(18, NB), 256, 0, stream>>>(src, dst,
            ln_g + l*ND, ln_b + l*ND,
            inw_b + (size_t)l*NHH*32, inb + l*NHH,
            dww + l*NH*7,
            mixw_b + (size_t)l*NH*64, mixb + l*NH,
            outw_b + (size_t)l*ND*NH, outb + l*ND);
    }
    kLN<<<NPOS, 256, 0, stream>>>(hA, olng, olnb);
}